// Round 19
// baseline (386.922 us; speedup 1.0000x reference)
//
#include <hip/hip_runtime.h>
#include <hip/hip_bf16.h>
#include <cmath>

constexpr int B  = 8;
constexpr int S  = 1024;
constexpr int P  = 128;
constexpr int D  = 256;
constexpr int H  = 4;
constexpr int L  = 4;
constexpr int DF = 1024;
constexpr int O  = 10;
constexpr int DH = D / H;       // 64
constexpr int SP = S + 1;       // 1025
constexpr int N  = B * SP;      // 8200
constexpr int KVPAD = 1088;     // 17*64

typedef short bf16x8 __attribute__((ext_vector_type(8)));
typedef float f32x4 __attribute__((ext_vector_type(4)));
typedef float f32x16 __attribute__((ext_vector_type(16)));
typedef unsigned int u32;
typedef unsigned short u16;

static __device__ __forceinline__ u16 f2b(float f) {
    __hip_bfloat16 h = __float2bfloat16(f);
    u16 u; __builtin_memcpy(&u, &h, 2);
    return u;
}
static __device__ __forceinline__ float b2f(u16 u) {
    u32 uu = (u32)u << 16; float f; __builtin_memcpy(&f, &uu, 4);
    return f;
}
static __device__ __forceinline__ u32 pk2(float a, float b) {
    return (u32)f2b(a) | ((u32)f2b(b) << 16);
}
static __device__ __forceinline__ void gload_lds16(const void* g, void* l) {
    __builtin_amdgcn_global_load_lds((const __attribute__((address_space(1))) unsigned int*)g,
                                     (__attribute__((address_space(3))) unsigned int*)l, 16, 0, 0);
}

// ---------------------------------------------------------------------------
// One launch: 4 f32->bf16 conversions (y=0..3) + fused QKV weight build (y=4).
// ---------------------------------------------------------------------------
__global__ void cvt_all(const float* __restrict__ s0, u16* __restrict__ d0, int n0,
                        const float* __restrict__ s1, u16* __restrict__ d1, int n1,
                        const float* __restrict__ s2, u16* __restrict__ d2, int n2,
                        const float* __restrict__ s3, u16* __restrict__ d3, int n3,
                        const float* __restrict__ Wq, const float* __restrict__ bq,
                        const float* __restrict__ Wk, const float* __restrict__ bk,
                        const float* __restrict__ Wv, const float* __restrict__ bv,
                        u16* __restrict__ Wout, float* __restrict__ bout) {
    int y = blockIdx.y;
    int i = blockIdx.x * 256 + threadIdx.x;
    if (y < 4) {
        const float* s = y == 0 ? s0 : y == 1 ? s1 : y == 2 ? s2 : s3;
        u16* d = y == 0 ? d0 : y == 1 ? d1 : y == 2 ? d2 : d3;
        int n = y == 0 ? n0 : y == 1 ? n1 : y == 2 ? n2 : n3;
        if (i < n) {
            float4 v = ((const float4*)s)[i];
            ushort4 o;
            o.x = f2b(v.x); o.y = f2b(v.y); o.z = f2b(v.z); o.w = f2b(v.w);
            ((ushort4*)d)[i] = o;
        }
        return;
    }
    // y == 4: build Wqkv (768*256 = 196608, NOT pow2 -> exact div/mod)
    if (i >= L * 768 * 256 / 4) return;
    int i4 = i * 4;
    int l = i4 / (768 * 256);
    int rem = i4 - l * (768 * 256);
    int r = rem >> 8, c = rem & 255;
    int sec = r >> 8;
    int ef = r & 255, h = ef >> 6, e = ef & 63;
    const float* W  = sec == 0 ? Wq : sec == 1 ? Wk : Wv;
    const float* bi = sec == 0 ? bq : sec == 1 ? bk : bv;
    float scale = sec == 0 ? 0.125f * 1.4426950408889634f : 1.0f;
    ushort4 o;
    if ((c >> 6) == h) {
        const float* wr = &W[(((size_t)l * H + h) * 64 + e) * 64 + (c & 63)];
        o.x = f2b(wr[0] * scale); o.y = f2b(wr[1] * scale);
        o.z = f2b(wr[2] * scale); o.w = f2b(wr[3] * scale);
    } else {
        o.x = o.y = o.z = o.w = f2b(0.f);
    }
    *(ushort4*)&Wout[((size_t)l * 768 + r) * 256 + c] = o;
    if (c == 0) bout[(size_t)l * 768 + r] = bi[((size_t)l * H + h) * 64 + e] * scale;
}

// ---------------------------------------------------------------------------
// MFMA GEMM, 2-phase global_load_lds pipeline. BM=64 BN=128 BK=64, 4 waves.
// EPI 0: patch-embed (row remap + pos, f32)   1: GELU -> bf16
//     3: plain bf16 store                     4: bf16 partial (split-K, no bias)
// ---------------------------------------------------------------------------
template <int EPI>
__global__ __launch_bounds__(256) void gemm_bf16(
        const u16* __restrict__ X, const u16* __restrict__ W,
        const float* __restrict__ bias, const float* __restrict__ pos,
        float* __restrict__ Yf, u16* __restrict__ Yb,
        int M, int F, int K, int kLen) {
    __shared__ u16 Al[2][64 * 64];
    __shared__ u16 Bl[2][128 * 64];
    const int t = threadIdx.x;
    const int m0 = blockIdx.y * 64, f0 = blockIdx.x * 128;
    const int w = t >> 6, l = t & 63;
    const int wm = w >> 1, wn = w & 1;
    const int q = l & 15, g = l >> 4;
    const int kOff = blockIdx.z * kLen;
    const int lr8 = l >> 3, lp = l & 7;

    f32x4 acc[2][4];
    const f32x4 zz = {0.f, 0.f, 0.f, 0.f};
#pragma unroll
    for (int i = 0; i < 2; ++i)
#pragma unroll
        for (int j = 0; j < 4; ++j) acc[i][j] = zz;

    auto stage = [&](int sb, int kbase) {
#pragma unroll
        for (int i = 0; i < 2; ++i) {
            int ca = w + 4 * i;
            int row = ca * 8 + lr8;
            int j = lp ^ (row & 7);
            gload_lds16(X + (size_t)(m0 + row) * K + kbase + j * 8, &Al[sb][ca * 512]);
        }
#pragma unroll
        for (int i = 0; i < 4; ++i) {
            int cb = w + 4 * i;
            int row = cb * 8 + lr8;
            int j = lp ^ (row & 7);
            gload_lds16(W + (size_t)(f0 + row) * K + kbase + j * 8, &Bl[sb][cb * 512]);
        }
    };

    const int nt = kLen / 64;
    stage(0, kOff);
    __syncthreads();
    int sb = 0;
    for (int ts = 0; ts < nt; ++ts) {
        if (ts + 1 < nt) stage(sb ^ 1, kOff + (ts + 1) * 64);
#pragma unroll
        for (int kk = 0; kk < 2; ++kk) {
            bf16x8 a[2], bfr[4];
#pragma unroll
            for (int fi = 0; fi < 2; ++fi) {
                int row = wm * 32 + fi * 16 + q;
                a[fi] = *(const bf16x8*)&Al[sb][row * 64 + (((kk * 4 + g) ^ (row & 7)) * 8)];
            }
#pragma unroll
            for (int fj = 0; fj < 4; ++fj) {
                int row = wn * 64 + fj * 16 + q;
                bfr[fj] = *(const bf16x8*)&Bl[sb][row * 64 + (((kk * 4 + g) ^ (row & 7)) * 8)];
            }
#pragma unroll
            for (int fi = 0; fi < 2; ++fi)
#pragma unroll
                for (int fj = 0; fj < 4; ++fj)
                    acc[fi][fj] = __builtin_amdgcn_mfma_f32_16x16x32_bf16(a[fi], bfr[fj], acc[fi][fj], 0, 0, 0);
        }
        __syncthreads();
        sb ^= 1;
    }

#pragma unroll
    for (int fi = 0; fi < 2; ++fi) {
#pragma unroll
        for (int r = 0; r < 4; ++r) {
            int m = m0 + wm * 32 + fi * 16 + g * 4 + r;
            if (m >= M) continue;
#pragma unroll
            for (int fj = 0; fj < 4; ++fj) {
                int f = f0 + wn * 64 + fj * 16 + q;
                float val = acc[fi][fj][r];
                if constexpr (EPI == 0) {
                    val += bias[f];
                    int s = m & 1023, bb = m >> 10;
                    size_t n = (size_t)bb * SP + s + 1;
                    Yf[n * D + f] = val + pos[(size_t)(s + 1) * D + f];
                } else if constexpr (EPI == 1) {
                    val += bias[f];
                    float gel = 0.5f * val * (1.0f + erff(val * 0.70710678118654752f));
                    Yb[(size_t)m * F + f] = f2b(gel);
                } else if constexpr (EPI == 3) {
                    val += bias[f];
                    Yb[(size_t)m * F + f] = f2b(val);
                } else {  // EPI 4: bf16 split-K partial, no bias
                    Yb[(size_t)blockIdx.z * M * F + (size_t)m * F + f] = f2b(val);
                }
            }
        }
    }
}

// ---------------------------------------------------------------------------
// V transpose: qkvbuf V section -> VTg[bh][d][kv]. grid (17, 32), 256 thr.
// ---------------------------------------------------------------------------
__global__ void transpose_v(const u16* __restrict__ qkv, u16* __restrict__ VTg) {
    __shared__ u16 tile[64][70];
    int bh = blockIdx.y, t0 = blockIdx.x * 64;
    int b = bh >> 2, h = bh & 3;
    int t = threadIdx.x;
    int r = t >> 3, c8 = (t & 7) * 8;
#pragma unroll
    for (int it = 0; it < 2; ++it) {
        int sp = t0 + it * 32 + r; if (sp > S) sp = S;
        uint4 v = *(const uint4*)(qkv + ((size_t)b * SP + sp) * 768 + 512 + h * 64 + c8);
        u32* dst = (u32*)&tile[it * 32 + r][c8];
        const u32* pv = (const u32*)&v;
#pragma unroll
        for (int k = 0; k < 4; ++k) dst[k] = pv[k];
    }
    __syncthreads();
#pragma unroll
    for (int it = 0; it < 2; ++it) {
        int d = it * 32 + (t >> 3);
        int spc = (t & 7) * 8;
        u16 tmp[8];
#pragma unroll
        for (int j = 0; j < 8; ++j) tmp[j] = tile[spc + j][d];
        *(uint4*)(VTg + ((size_t)bh * 64 + d) * KVPAD + t0 + spc) = *(const uint4*)tmp;
    }
}

// ---------------------------------------------------------------------------
// First LayerNorm with fused cls-row creation. grid N/4, 256 thr.
// ---------------------------------------------------------------------------
__global__ void ln_first(const float* __restrict__ cls, const float* __restrict__ pos,
                         const float* __restrict__ gw, const float* __restrict__ bw,
                         float* __restrict__ x, u16* __restrict__ dst) {
    int row = blockIdx.x * 4 + (threadIdx.x >> 6);
    int l = threadIdx.x & 63;
    float4 v;
    if ((row % SP) == 0) {          // wave-uniform
        float4 c = *(const float4*)(cls + l * 4);
        float4 pp = *(const float4*)(pos + l * 4);
        v.x = c.x + pp.x; v.y = c.y + pp.y; v.z = c.z + pp.z; v.w = c.w + pp.w;
        *(float4*)(x + (size_t)row * D + l * 4) = v;
    } else {
        v = *(const float4*)(x + (size_t)row * D + l * 4);
    }
    float s = v.x + v.y + v.z + v.w;
    for (int off = 32; off; off >>= 1) s += __shfl_xor(s, off, 64);
    float mean = s * (1.0f / D);
    float dx0 = v.x - mean, dx1 = v.y - mean, dx2 = v.z - mean, dx3 = v.w - mean;
    float sq = dx0 * dx0 + dx1 * dx1 + dx2 * dx2 + dx3 * dx3;
    for (int off = 32; off; off >>= 1) sq += __shfl_xor(sq, off, 64);
    float rs = rsqrtf(sq * (1.0f / D) + 1e-5f);
    float4 gv = *(const float4*)(gw + l * 4);
    float4 bv = *(const float4*)(bw + l * 4);
    ushort4 o;
    o.x = f2b(dx0 * rs * gv.x + bv.x);
    o.y = f2b(dx1 * rs * gv.y + bv.y);
    o.z = f2b(dx2 * rs * gv.z + bv.z);
    o.w = f2b(dx3 * rs * gv.w + bv.w);
    *(ushort4*)(dst + (size_t)row * D + l * 4) = o;
}

// ---------------------------------------------------------------------------
// Flash attention, stage-once, 8-wave blocks, XCD-swizzled 1D grid.
// Main loop now compile-time specialized: quarters 0-2 run an UNROLLED 4-tile
// path with no masking (kv_len=256 statically full); quarter 3 runs unrolled
// 4 full tiles + 1 masked tail tile. Unrolling lets the scheduler hoist tile
// t+1's ds_reads under tile t's softmax/PV chain.
// ---------------------------------------------------------------------------
__global__ __launch_bounds__(512, 4) void attn_stage(const u16* __restrict__ qkv,
                                                     const u16* __restrict__ VTg,
                                                     u16* __restrict__ opart,
                                                     float* __restrict__ lsum,
                                                     int nqt, int ngq) {
    const int bid = blockIdx.x;
    const int xcd = bid & 7, t2 = bid >> 3;
    const int g128 = xcd + 8 * (t2 / ngq);
    const int qg = t2 % ngq;
    const int quarter = g128 >> 5, bh = g128 & 31;
    const int h4 = bh & 3, b = bh >> 2;
    const int t = threadIdx.x;
    const int wv = t >> 6, l = t & 63;
    const int col = l & 31, hh = l >> 5;

    __shared__ u16 Kl[5 * 64 * 64];
    __shared__ u16 Vl[5 * 64 * 64];

    const int kv_start = quarter * 256;
    const int ntiles = (quarter == 3) ? 5 : 4;

    const int qt = qg * 8 + wv;            // this wave's q-tile
    const int q0w = qt * 32;

    bf16x8 qf[4];
    {
        int qr = q0w + col; if (qr > S) qr = S;
        const u16* qp = qkv + ((size_t)b * SP + qr) * 768 + h4 * 64 + hh * 8;
#pragma unroll
        for (int c = 0; c < 4; ++c) qf[c] = *(const bf16x8*)(qp + c * 16);
    }

    {
        const int rloc = wv * 8 + (l >> 3);
        const int j = (l & 7) ^ (((rloc >> 3) ^ rloc) & 7);
        for (int tt = 0; tt < ntiles; ++tt) {
            int krow = kv_start + tt * 64 + rloc; if (krow > S) krow = S;
            gload_lds16(qkv + ((size_t)b * SP + krow) * 768 + 256 + h4 * 64 + j * 8,
                        &Kl[(tt * 8 + wv) * 512]);
            gload_lds16(VTg + ((size_t)bh * 64 + rloc) * KVPAD + kv_start + tt * 64 + j * 8,
                        &Vl[(tt * 8 + wv) * 512]);
        }
    }
    __syncthreads();
    if (qt >= nqt) return;

    const int swA = ((col >> 3) ^ col) & 7;
    const int swB = swA ^ 4;

    f32x16 o0, o1;
#pragma unroll
    for (int r = 0; r < 16; ++r) { o0[r] = 0.f; o1[r] = 0.f; }
    float l_run = 0.f;

    // per-tile body; MASK only for the quarter-3 tail tile (kv_len = 257)
    auto tile_body = [&](int tile, bool mask) {
        const int kv0 = tile * 64;
        const u16* Kt = &Kl[tile * 4096];
        const u16* Vt = &Vl[tile * 4096];

        f32x16 s0, s1;
#pragma unroll
        for (int r = 0; r < 16; ++r) { s0[r] = 0.f; s1[r] = 0.f; }
        __builtin_amdgcn_s_setprio(1);
#pragma unroll
        for (int c = 0; c < 4; ++c) {
            bf16x8 k0 = *(const bf16x8*)&Kt[col * 64 + (((2 * c + hh) ^ swA) * 8)];
            bf16x8 k1 = *(const bf16x8*)&Kt[(32 + col) * 64 + (((2 * c + hh) ^ swB) * 8)];
            s0 = __builtin_amdgcn_mfma_f32_32x32x16_bf16(k0, qf[c], s0, 0, 0, 0);
            s1 = __builtin_amdgcn_mfma_f32_32x32x16_bf16(k1, qf[c], s1, 0, 0, 0);
        }
        __builtin_amdgcn_s_setprio(0);

        float p[32];
#pragma unroll
        for (int r = 0; r < 16; ++r) { p[r] = s0[r]; p[16 + r] = s1[r]; }

        if (mask) {
#pragma unroll
            for (int kvs = 0; kvs < 2; ++kvs)
#pragma unroll
                for (int r = 0; r < 16; ++r) {
                    int kvloc = kvs * 32 + (r & 3) + 8 * (r >> 2) + 4 * hh;
                    if (kv0 + kvloc >= 257) p[kvs * 16 + r] = -1e30f;
                }
        }

#pragma unroll
        for (int j = 0; j < 32; ++j) p[j] = exp2f(p[j]);
        {
            float t16[16];
#pragma unroll
            for (int j = 0; j < 16; ++j) t16[j] = p[2 * j] + p[2 * j + 1];
#pragma unroll
            for (int j = 0; j < 8; ++j) t16[j] = t16[j] + t16[j + 8];
#pragma unroll
            for (int j = 0; j < 4; ++j) t16[j] = t16[j] + t16[j + 4];
            l_run += (t16[0] + t16[1]) + (t16[2] + t16[3]);
        }

        __builtin_amdgcn_s_setprio(1);
#pragma unroll
        for (int kvs = 0; kvs < 2; ++kvs) {
            u32 pk[8];
#pragma unroll
            for (int i = 0; i < 8; ++i) pk[i] = pk2(p[kvs * 16 + 2 * i], p[kvs * 16 + 2 * i + 1]);
            u32 ex[4];
#pragma unroll
            for (int kk = 0; kk < 4; ++kk) {
                const int k = (kk < 2) ? kk : kk + 2;
                u32 send = hh ? pk[k] : pk[k + 2];
                ex[kk] = (u32)__shfl_xor((int)send, 32);
            }
#pragma unroll
            for (int cc = 0; cc < 2; ++cc) {
                union { u32 u[4]; bf16x8 v; } pa;
                u32 e0 = ex[cc * 2], e1 = ex[cc * 2 + 1];
                pa.u[0] = hh ? e0 : pk[4 * cc];
                pa.u[1] = hh ? e1 : pk[4 * cc + 1];
                pa.u[2] = hh ? pk[4 * cc + 2] : e0;
                pa.u[3] = hh ? pk[4 * cc + 3] : e1;
                int lch = kvs * 4 + cc * 2 + hh;
                bf16x8 v0 = *(const bf16x8*)&Vt[col * 64 + ((lch ^ swA) * 8)];
                bf16x8 v1 = *(const bf16x8*)&Vt[(32 + col) * 64 + ((lch ^ swB) * 8)];
                o0 = __builtin_amdgcn_mfma_f32_32x32x16_bf16(pa.v, v0, o0, 0, 0, 0);
                o1 = __builtin_amdgcn_mfma_f32_32x32x16_bf16(pa.v, v1, o1, 0, 0, 0);
            }
        }
        __builtin_amdgcn_s_setprio(0);
    };

    if (quarter < 3) {
#pragma unroll
        for (int tile = 0; tile < 4; ++tile) tile_body(tile, false);
    } else {
#pragma unroll
        for (int tile = 0; tile < 4; ++tile) tile_body(tile, false);
        tile_body(4, true);
    }

    float l_full = l_run + __shfl_xor(l_run, 32);
    const size_t obase = ((size_t)quarter * 32 + bh) * SP;
#pragma unroll
    for (int r = 0; r < 16; ++r) {
        int qrow = (r & 3) + 8 * (r >> 2) + 4 * hh;
        int qq = q0w + qrow;
        if (qq < SP) {
            opart[(obase + qq) * 64 + col]      = f2b(o0[r]);
            opart[(obase + qq) * 64 + 32 + col] = f2b(o1[r]);
        }
    }
    if (l < 32) {
        int qq = q0w + l;
        if (qq < SP) lsum[obase + qq] = l_full;
    }
}

// ---------------------------------------------------------------------------
// Fused: x += (Σ raw partials)/(Σ l); lnb = LN2(x).
// ---------------------------------------------------------------------------
__global__ void combine_ln2(const u16* __restrict__ opart, const float* __restrict__ lsum,
                            const float* __restrict__ gw, const float* __restrict__ bw,
                            float* __restrict__ x, u16* __restrict__ lnb) {
    int row = blockIdx.x * 4 + (threadIdx.x >> 6);
    int l = threadIdx.x & 63;
    int b = row / SP, qq = row % SP;
    int h = l >> 4, d0 = (l * 4) & 63;
    int bh = b * 4 + h;
    float csum = 0.f, a0 = 0.f, a1 = 0.f, a2 = 0.f, a3 = 0.f;
#pragma unroll
    for (int i = 0; i < 4; ++i) {
        size_t idx = ((size_t)i * 32 + bh) * SP + qq;
        csum += lsum[idx];
        ushort4 ov = *(const ushort4*)&opart[idx * 64 + d0];
        a0 += b2f(ov.x); a1 += b2f(ov.y); a2 += b2f(ov.z); a3 += b2f(ov.w);
    }
    float inv = 1.0f / csum;
    float4 xv = *(const float4*)(x + (size_t)row * D + l * 4);
    xv.x += a0 * inv; xv.y += a1 * inv; xv.z += a2 * inv; xv.w += a3 * inv;
    *(float4*)(x + (size_t)row * D + l * 4) = xv;

    float s = xv.x + xv.y + xv.z + xv.w;
    for (int off = 32; off; off >>= 1) s += __shfl_xor(s, off, 64);
    float mean = s * (1.0f / D);
    float dx0 = xv.x - mean, dx1 = xv.y - mean, dx2 = xv.z - mean, dx3 = xv.w - mean;
    float sq = dx0 * dx0 + dx1 * dx1 + dx2 * dx2 + dx3 * dx3;
    for (int off = 32; off; off >>= 1) sq += __shfl_xor(sq, off, 64);
    float rs = rsqrtf(sq * (1.0f / D) + 1e-5f);
    float4 gv = *(const float4*)(gw + l * 4);
    float4 bv = *(const float4*)(bw + l * 4);
    ushort4 o;
    o.x = f2b(dx0 * rs * gv.x + bv.x);
    o.y = f2b(dx1 * rs * gv.y + bv.y);
    o.z = f2b(dx2 * rs * gv.z + bv.z);
    o.w = f2b(dx3 * rs * gv.w + bv.w);
    *(ushort4*)(lnb + (size_t)row * D + l * 4) = o;
}

// ---------------------------------------------------------------------------
// Fused: x += Pk0 + Pk1 + b2 (bf16 partials); lnb = LN1_{l+1}(x).
// ---------------------------------------------------------------------------
__global__ void combine2_ln1(const u16* __restrict__ Pkb, const float* __restrict__ b2,
                             const float* __restrict__ gw, const float* __restrict__ bw,
                             float* __restrict__ x, u16* __restrict__ lnb) {
    int row = blockIdx.x * 4 + (threadIdx.x >> 6);
    int l = threadIdx.x & 63;
    ushort4 p0 = *(const ushort4*)(Pkb + (size_t)row * D + l * 4);
    ushort4 p1 = *(const ushort4*)(Pkb + (size_t)N * D + (size_t)row * D + l * 4);
    float4 bv2 = *(const float4*)(b2 + l * 4);
    float4 xv = *(const float4*)(x + (size_t)row * D + l * 4);
    xv.x += b2f(p0.x) + b2f(p1.x) + bv2.x;
    xv.y += b2f(p0.y) + b2f(p1.y) + bv2.y;
    xv.z += b2f(p0.z) + b2f(p1.z) + bv2.z;
    xv.w += b2f(p0.w) + b2f(p1.w) + bv2.w;
    *(float4*)(x + (size_t)row * D + l * 4) = xv;

    float s = xv.x + xv.y + xv.z + xv.w;
    for (int off = 32; off; off >>= 1) s += __shfl_xor(s, off, 64);
    float mean = s * (1.0f / D);
    float dx0 = xv.x - mean, dx1 = xv.y - mean, dx2 = xv.z - mean, dx3 = xv.w - mean;
    float sq = dx0 * dx0 + dx1 * dx1 + dx2 * dx2 + dx3 * dx3;
    for (int off = 32; off; off >>= 1) sq += __shfl_xor(sq, off, 64);
    float rs = rsqrtf(sq * (1.0f / D) + 1e-5f);
    float4 gv = *(const float4*)(gw + l * 4);
    float4 bv = *(const float4*)(bw + l * 4);
    ushort4 o;
    o.x = f2b(dx0 * rs * gv.x + bv.x);
    o.y = f2b(dx1 * rs * gv.y + bv.y);
    o.z = f2b(dx2 * rs * gv.z + bv.z);
    o.w = f2b(dx3 * rs * gv.w + bv.w);
    *(ushort4*)(lnb + (size_t)row * D + l * 4) = o;
}

// ---------------------------------------------------------------------------
// Tail: mlp1 + GELU with fused cls combine + LN2 prologue.
// grid (8 f-chunks, B), 256 thr; fc==0 also writes xc.
// ---------------------------------------------------------------------------
__global__ void tail_mlp1(const u16* __restrict__ opart, const float* __restrict__ lsum,
                          const float* __restrict__ x,
                          const float* __restrict__ g2, const float* __restrict__ b2w,
                          const u16* __restrict__ W1l, const float* __restrict__ b1l,
                          float* __restrict__ xc, float* __restrict__ midc) {
    __shared__ float ln[256];
    __shared__ float red[4];
    const int fc = blockIdx.x, b = blockIdx.y, t = threadIdx.x;
    const int h = t >> 6, dl = t & 63;

    float csum = 0.f, a = 0.f;
#pragma unroll
    for (int i = 0; i < 4; ++i) {
        size_t idx = ((size_t)i * 32 + b * 4 + h) * SP;
        csum += lsum[idx];
        a += b2f(opart[idx * 64 + dl]);
    }
    float xv = x[(size_t)b * SP * D + t] + a / csum;
    if (fc == 0) xc[b * D + t] = xv;

    float s = xv;
    for (int off = 32; off; off >>= 1) s += __shfl_xor(s, off, 64);
    if ((t & 63) == 0) red[t >> 6] = s;
    __syncthreads();
    float mean = (red[0] + red[1] + red[2] + red[3]) * (1.0f / D);
    float dx = xv - mean;
    float sq = dx * dx;
    for (int off = 32; off; off >>= 1) sq += __shfl_xor(sq, off, 64);
    __syncthreads();
    if ((t & 63) == 0) red[t >> 6] = sq;
    __syncthreads();
    float var = (red[0] + red[1] + red[2] + red[3]) * (1.0f / D);
    ln[t] = dx * rsqrtf(var + 1e-5f) * g2[t] + b2w[t];
    __syncthreads();

    const int f = fc * 128 + (t >> 1);
    const int half = t & 1;
    const u16* wr = W1l + (size_t)f * D + half * 128;
    const float* lp = &ln[half * 128];
    float acc = 0.f;
#pragma unroll
    for (int d = 0; d < 128; d += 8) {
        bf16x8 wv = *(const bf16x8*)(wr + d);
        const u16* wu = (const u16*)&wv;
#pragma unroll
        for (int j = 0; j < 8; ++j) acc += lp[d + j] * b2f(wu[j]);
    }
    acc += __shfl_xor(acc, 1);
    if (half == 0) {
        float v = acc + b1l[f];
        midc[b * DF + f] = 0.5f * v * (1.0f + erff(v * 0.70710678118654752f));
    }
}

// ---------------------------------------------------------------------------
// Tail stage 3: mlp2 residual. grid (8 d-chunks, B), 256 thr; 8 thr per output.
// ---------------------------------------------------------------------------
__global__ void tail_mlp2(const float* __restrict__ midc,
                          const u16* __restrict__ W2l, const float* __restrict__ b2l,
                          const float* __restrict__ xc, float* __restrict__ xc2) {
    __shared__ float mh[1024];
    const int dc = blockIdx.x, b = blockIdx.y, t = threadIdx.x;
#pragma unroll
    for (int i = 0; i < 4; ++i) mh[t + i * 256] = midc[b * DF + t + i * 256];
    __syncthreads();
    const int dout = dc * 32 + (t >> 3);
    const int oct = t & 7;
    const u16* wr = W2l + (size_t)dout * DF + oct * 128;
    const float* mp = &mh[oct * 128];
    float acc = 0.f;
#pragma unroll
    for (int f = 0; f < 128; f += 8) {
        bf16x8 wv = *(const bf16x8*)(wr + f);
        const u16* wu = (const u16*)&wv;
#pragma unroll
        for (int j = 0; j < 8; ++j) acc += mp[f + j] * b2f(wu[j]);
    }
    acc += __shfl_xor(acc, 1);
    acc += __shfl_xor(acc, 2);
    acc += __shfl_xor(acc, 4);
    if (oct == 0) xc2[b * D + dout] = xc[b * D + dout] + acc + b2l[dout];
}

// ---------------------------------------------------------------------------
__global__ void head_kernel(const float* __restrict__ xc,
                            const float* __restrict__ Wo,
                            const float* __restrict__ bo,
                            float* __restrict__ out) {
    __shared__ float logits[B][O];
    int t = threadIdx.x;
    if (t < B * O) {
        int b = t / O, o = t % O;
        const float* xr = xc + (size_t)b * D;
        float acc = bo[o];
        for (int d = 0; d < D; ++d) acc += xr[d] * Wo[(size_t)o * D + d];
        logits[b][o] = acc;
    }
    __syncthreads();
    if (t < B) {
        float mx = -1e30f;
        for (int o = 0; o < O; ++o) mx = fmaxf(mx, logits[t][o]);
        float s = 0.f, e[O];
        for (int o = 0; o < O; ++o) { e[o] = expf(logits[t][o] - mx); s += e[o]; }
        float inv = 1.0f / s;
        for (int o = 0; o < O; ++o) out[t * O + o] = e[o] * inv;
    }
}

// ---------------------------------------------------------------------------
extern "C" void kernel_launch(void* const* d_in, const int* in_sizes, int n_in,
                              void* d_out, int out_size, void* d_ws, size_t ws_size,
                              hipStream_t stream) {
    const float* images = (const float*)d_in[0];
    const float* Wp     = (const float*)d_in[1];
    const float* bp     = (const float*)d_in[2];
    const float* cls    = (const float*)d_in[3];
    const float* pos    = (const float*)d_in[4];
    const float* ln1_g  = (const float*)d_in[5];
    const float* ln1_b  = (const float*)d_in[6];
    const float* Wq     = (const float*)d_in[7];
    const float* bq     = (const float*)d_in[8];
    const float* Wk     = (const float*)d_in[9];
    const float* bk     = (const float*)d_in[10];
    const float* Wv     = (const float*)d_in[11];
    const float* bv     = (const float*)d_in[12];
    const float* ln2_g  = (const float*)d_in[13];
    const float* ln2_b  = (const float*)d_in[14];
    const float* W1     = (const float*)d_in[15];
    const float* b1     = (const float*)d_in[16];
    const float* W2     = (const float*)d_in[17];
    const float* b2     = (const float*)d_in[18];
    const float* Wo     = (const float*)d_in[19];
    const float* bo     = (const float*)d_in[20];
    float* out = (float*)d_out;

    auto align256 = [](size_t v) { return (v + 255) & ~(size_t)255; };
    char* p = (char*)d_ws;
    float* x      = (float*)p; p += align256((size_t)N * D * 4);
    u16* lnb      = (u16*)p;   p += align256((size_t)N * D * 2);
    u16* qkvbuf   = (u16*)p;   p += align256((size_t)(N + 128) * 768 * 2);  // pad rows
    char* midop   = p;         p += align256((size_t)N * DF * 2);   // mid bf16 / opart bf16 alias
    u16* Pkb      = (u16*)p;   p += align256((size_t)2 * N * D * 2);
    float* lsum   = (float*)p; p += align256((size_t)4 * 32 * SP * 4);
    u16* VTg      = (u16*)p;   p += align256((size_t)32 * 64 * KVPAD * 2);
    u16* imgb     = (u16*)p;   p += align256((size_t)B * S * P * 2);
    u16* Wpb      = (u16*)p;   p += align256((size_t)D * P * 2);
    u16* W1b      = (u16*)p;   p += align256((size_t)L * DF * D * 2);
    u16* W2b      = (u16*)p;   p += align256((size_t)L * D * DF * 2);
    u16* Wqkvb    = (u16*)p;   p += align256((size_t)L * 768 * 256 * 2);
    float* bqkvf  = (float*)p; p += align256((size_t)L * 768 * 4);
    float* xc     = (float*)p; p += align256((size_t)B * D * 4);
    float* midc   = (float*)p; p += align256((size_t)B * DF * 4);
    float* xc2    = (float*)p; p += align256((size_t)B * D * 4);
    u16* mid      = (u16*)midop;
    u16* opart    = (u16*)midop;

    // one-time conversions + QKV weight build (single launch)
    cvt_all<<<dim3(1024, 5), 256, 0, stream>>>(
        images, imgb, B * S * P / 4,
        Wp, Wpb, D * P / 4,
        W1, W1b, L * DF * D / 4,
        W2, W2b, L * D * DF / 4,
        Wq, bq, Wk, bk, Wv, bv, Wqkvb, bqkvf);

    // patch embed as GEMM (M=8192, F=256, K=128); cls + LN1_0 fused
    gemm_bf16<0><<<dim3(2, 128, 1), 256, 0, stream>>>(
        imgb, Wpb, bp, pos, x, nullptr, B * S, D, P, P);
    ln_first<<<N / 4, 256, 0, stream>>>(cls, pos, ln1_g, ln1_b, x, lnb);

    for (int l = 0; l < 3; ++l) {
        gemm_bf16<3><<<dim3(6, 129, 1), 256, 0, stream>>>(
            lnb, Wqkvb + (size_t)l * 768 * 256, bqkvf + (size_t)l * 768,
            nullptr, nullptr, qkvbuf, N, 768, D, D);
        transpose_v<<<dim3(17, 32), 256, 0, stream>>>(qkvbuf, VTg);
        attn_stage<<<640, 512, 0, stream>>>(qkvbuf, VTg, opart, lsum, 33, 5);
        combine_ln2<<<N / 4, 256, 0, stream>>>(opart, lsum, ln2_g + l * D, ln2_b + l * D, x, lnb);
        gemm_bf16<1><<<dim3(8, 129, 1), 256, 0, stream>>>(
            lnb, W1b + (size_t)l * DF * D, b1 + (size_t)l * DF,
            nullptr, nullptr, mid, N, DF, D, D);
        gemm_bf16<4><<<dim3(2, 129, 2), 256, 0, stream>>>(
            mid, W2b + (size_t)l * D * DF, nullptr, nullptr, nullptr, Pkb, N, D, DF, DF / 2);
        combine2_ln1<<<N / 4, 256, 0, stream>>>(Pkb, b2 + (size_t)l * D,
                                                ln1_g + (l + 1) * D, ln1_b + (l + 1) * D, x, lnb);
    }

    // layer 3: only cls rows matter downstream
    {
        const int l = 3;
        gemm_bf16<3><<<dim3(6, 129, 1), 256, 0, stream>>>(
            lnb, Wqkvb + (size_t)l * 768 * 256, bqkvf + (size_t)l * 768,
            nullptr, nullptr, qkvbuf, N, 768, D, D);
        transpose_v<<<dim3(17, 32), 256, 0, stream>>>(qkvbuf, VTg);
        attn_stage<<<128, 512, 0, stream>>>(qkvbuf, VTg, opart, lsum, 1, 1);
        tail_mlp1<<<dim3(8, B), 256, 0, stream>>>(opart, lsum, x,
                                                  ln2_g + l * D, ln2_b + l * D,
                                                  W1b + (size_t)l * DF * D, b1 + (size_t)l * DF,
                                                  xc, midc);
        tail_mlp2<<<dim3(8, B), 256, 0, stream>>>(midc, W2b + (size_t)l * D * DF,
                                                  b2 + (size_t)l * D, xc, xc2);
        head_kernel<<<1, 256, 0, stream>>>(xc2, Wo, bo, out);
    }
}

// Round 20
// 327.414 us; speedup vs baseline: 1.1818x; 1.1818x over previous
//
#include <hip/hip_runtime.h>
#include <hip/hip_bf16.h>
#include <cmath>

constexpr int B  = 8;
constexpr int S  = 1024;
constexpr int P  = 128;
constexpr int D  = 256;
constexpr int H  = 4;
constexpr int L  = 4;
constexpr int DF = 1024;
constexpr int O  = 10;
constexpr int DH = D / H;       // 64
constexpr int SP = S + 1;       // 1025
constexpr int N  = B * SP;      // 8200
constexpr int KVPAD = 1088;     // 17*64

typedef short bf16x8 __attribute__((ext_vector_type(8)));
typedef float f32x4 __attribute__((ext_vector_type(4)));
typedef float f32x16 __attribute__((ext_vector_type(16)));
typedef unsigned int u32;
typedef unsigned short u16;

static __device__ __forceinline__ u16 f2b(float f) {
    __hip_bfloat16 h = __float2bfloat16(f);
    u16 u; __builtin_memcpy(&u, &h, 2);
    return u;
}
static __device__ __forceinline__ float b2f(u16 u) {
    u32 uu = (u32)u << 16; float f; __builtin_memcpy(&f, &uu, 4);
    return f;
}
static __device__ __forceinline__ u32 pk2(float a, float b) {
    return (u32)f2b(a) | ((u32)f2b(b) << 16);
}
static __device__ __forceinline__ void gload_lds16(const void* g, void* l) {
    __builtin_amdgcn_global_load_lds((const __attribute__((address_space(1))) unsigned int*)g,
                                     (__attribute__((address_space(3))) unsigned int*)l, 16, 0, 0);
}

// ---------------------------------------------------------------------------
// One launch: 4 f32->bf16 conversions (y=0..3) + fused QKV weight build (y=4).
// QKV weight: Wout[l][768][256] bf16, Q rows scaled 0.125*log2(e); bias bout.
// ---------------------------------------------------------------------------
__global__ void cvt_all(const float* __restrict__ s0, u16* __restrict__ d0, int n0,
                        const float* __restrict__ s1, u16* __restrict__ d1, int n1,
                        const float* __restrict__ s2, u16* __restrict__ d2, int n2,
                        const float* __restrict__ s3, u16* __restrict__ d3, int n3,
                        const float* __restrict__ Wq, const float* __restrict__ bq,
                        const float* __restrict__ Wk, const float* __restrict__ bk,
                        const float* __restrict__ Wv, const float* __restrict__ bv,
                        u16* __restrict__ Wout, float* __restrict__ bout) {
    int y = blockIdx.y;
    int i = blockIdx.x * 256 + threadIdx.x;
    if (y < 4) {
        const float* s = y == 0 ? s0 : y == 1 ? s1 : y == 2 ? s2 : s3;
        u16* d = y == 0 ? d0 : y == 1 ? d1 : y == 2 ? d2 : d3;
        int n = y == 0 ? n0 : y == 1 ? n1 : y == 2 ? n2 : n3;
        if (i < n) {
            float4 v = ((const float4*)s)[i];
            ushort4 o;
            o.x = f2b(v.x); o.y = f2b(v.y); o.z = f2b(v.z); o.w = f2b(v.w);
            ((ushort4*)d)[i] = o;
        }
        return;
    }
    // y == 4: build Wqkv (768*256 = 196608, NOT pow2 -> exact div/mod)
    if (i >= L * 768 * 256 / 4) return;
    int i4 = i * 4;
    int l = i4 / (768 * 256);
    int rem = i4 - l * (768 * 256);
    int r = rem >> 8, c = rem & 255;
    int sec = r >> 8;
    int ef = r & 255, h = ef >> 6, e = ef & 63;
    const float* W  = sec == 0 ? Wq : sec == 1 ? Wk : Wv;
    const float* bi = sec == 0 ? bq : sec == 1 ? bk : bv;
    float scale = sec == 0 ? 0.125f * 1.4426950408889634f : 1.0f;
    ushort4 o;
    if ((c >> 6) == h) {
        const float* wr = &W[(((size_t)l * H + h) * 64 + e) * 64 + (c & 63)];
        o.x = f2b(wr[0] * scale); o.y = f2b(wr[1] * scale);
        o.z = f2b(wr[2] * scale); o.w = f2b(wr[3] * scale);
    } else {
        o.x = o.y = o.z = o.w = f2b(0.f);
    }
    *(ushort4*)&Wout[((size_t)l * 768 + r) * 256 + c] = o;
    if (c == 0) bout[(size_t)l * 768 + r] = bi[((size_t)l * H + h) * 64 + e] * scale;
}

// ---------------------------------------------------------------------------
// MFMA GEMM, 2-phase global_load_lds pipeline. BM=64 BN=128 BK=64, 4 waves.
// EPI 0: patch-embed (row remap + pos, f32)   1: GELU -> bf16
//     3: plain bf16 store                     4: bf16 partial (split-K, no bias)
// ---------------------------------------------------------------------------
template <int EPI>
__global__ __launch_bounds__(256) void gemm_bf16(
        const u16* __restrict__ X, const u16* __restrict__ W,
        const float* __restrict__ bias, const float* __restrict__ pos,
        float* __restrict__ Yf, u16* __restrict__ Yb,
        int M, int F, int K, int kLen) {
    __shared__ u16 Al[2][64 * 64];
    __shared__ u16 Bl[2][128 * 64];
    const int t = threadIdx.x;
    const int m0 = blockIdx.y * 64, f0 = blockIdx.x * 128;
    const int w = t >> 6, l = t & 63;
    const int wm = w >> 1, wn = w & 1;
    const int q = l & 15, g = l >> 4;
    const int kOff = blockIdx.z * kLen;
    const int lr8 = l >> 3, lp = l & 7;

    f32x4 acc[2][4];
    const f32x4 zz = {0.f, 0.f, 0.f, 0.f};
#pragma unroll
    for (int i = 0; i < 2; ++i)
#pragma unroll
        for (int j = 0; j < 4; ++j) acc[i][j] = zz;

    auto stage = [&](int sb, int kbase) {
#pragma unroll
        for (int i = 0; i < 2; ++i) {
            int ca = w + 4 * i;
            int row = ca * 8 + lr8;
            int j = lp ^ (row & 7);
            gload_lds16(X + (size_t)(m0 + row) * K + kbase + j * 8, &Al[sb][ca * 512]);
        }
#pragma unroll
        for (int i = 0; i < 4; ++i) {
            int cb = w + 4 * i;
            int row = cb * 8 + lr8;
            int j = lp ^ (row & 7);
            gload_lds16(W + (size_t)(f0 + row) * K + kbase + j * 8, &Bl[sb][cb * 512]);
        }
    };

    const int nt = kLen / 64;
    stage(0, kOff);
    __syncthreads();
    int sb = 0;
    for (int ts = 0; ts < nt; ++ts) {
        if (ts + 1 < nt) stage(sb ^ 1, kOff + (ts + 1) * 64);
#pragma unroll
        for (int kk = 0; kk < 2; ++kk) {
            bf16x8 a[2], bfr[4];
#pragma unroll
            for (int fi = 0; fi < 2; ++fi) {
                int row = wm * 32 + fi * 16 + q;
                a[fi] = *(const bf16x8*)&Al[sb][row * 64 + (((kk * 4 + g) ^ (row & 7)) * 8)];
            }
#pragma unroll
            for (int fj = 0; fj < 4; ++fj) {
                int row = wn * 64 + fj * 16 + q;
                bfr[fj] = *(const bf16x8*)&Bl[sb][row * 64 + (((kk * 4 + g) ^ (row & 7)) * 8)];
            }
#pragma unroll
            for (int fi = 0; fi < 2; ++fi)
#pragma unroll
                for (int fj = 0; fj < 4; ++fj)
                    acc[fi][fj] = __builtin_amdgcn_mfma_f32_16x16x32_bf16(a[fi], bfr[fj], acc[fi][fj], 0, 0, 0);
        }
        __syncthreads();
        sb ^= 1;
    }

#pragma unroll
    for (int fi = 0; fi < 2; ++fi) {
#pragma unroll
        for (int r = 0; r < 4; ++r) {
            int m = m0 + wm * 32 + fi * 16 + g * 4 + r;
            if (m >= M) continue;
#pragma unroll
            for (int fj = 0; fj < 4; ++fj) {
                int f = f0 + wn * 64 + fj * 16 + q;
                float val = acc[fi][fj][r];
                if constexpr (EPI == 0) {
                    val += bias[f];
                    int s = m & 1023, bb = m >> 10;
                    size_t n = (size_t)bb * SP + s + 1;
                    Yf[n * D + f] = val + pos[(size_t)(s + 1) * D + f];
                } else if constexpr (EPI == 1) {
                    val += bias[f];
                    float gel = 0.5f * val * (1.0f + erff(val * 0.70710678118654752f));
                    Yb[(size_t)m * F + f] = f2b(gel);
                } else if constexpr (EPI == 3) {
                    val += bias[f];
                    Yb[(size_t)m * F + f] = f2b(val);
                } else {  // EPI 4: bf16 split-K partial, no bias
                    Yb[(size_t)blockIdx.z * M * F + (size_t)m * F + f] = f2b(val);
                }
            }
        }
    }
}

// ---------------------------------------------------------------------------
// V transpose: qkvbuf V section -> VTg[bh][d][kv]. grid (17, 32), 256 thr.
// ---------------------------------------------------------------------------
__global__ void transpose_v(const u16* __restrict__ qkv, u16* __restrict__ VTg) {
    __shared__ u16 tile[64][70];
    int bh = blockIdx.y, t0 = blockIdx.x * 64;
    int b = bh >> 2, h = bh & 3;
    int t = threadIdx.x;
    int r = t >> 3, c8 = (t & 7) * 8;
#pragma unroll
    for (int it = 0; it < 2; ++it) {
        int sp = t0 + it * 32 + r; if (sp > S) sp = S;
        uint4 v = *(const uint4*)(qkv + ((size_t)b * SP + sp) * 768 + 512 + h * 64 + c8);
        u32* dst = (u32*)&tile[it * 32 + r][c8];
        const u32* pv = (const u32*)&v;
#pragma unroll
        for (int k = 0; k < 4; ++k) dst[k] = pv[k];
    }
    __syncthreads();
#pragma unroll
    for (int it = 0; it < 2; ++it) {
        int d = it * 32 + (t >> 3);
        int spc = (t & 7) * 8;
        u16 tmp[8];
#pragma unroll
        for (int j = 0; j < 8; ++j) tmp[j] = tile[spc + j][d];
        *(uint4*)(VTg + ((size_t)bh * 64 + d) * KVPAD + t0 + spc) = *(const uint4*)tmp;
    }
}

// ---------------------------------------------------------------------------
// First LayerNorm with fused cls-row creation. grid N/4, 256 thr.
// ---------------------------------------------------------------------------
__global__ void ln_first(const float* __restrict__ cls, const float* __restrict__ pos,
                         const float* __restrict__ gw, const float* __restrict__ bw,
                         float* __restrict__ x, u16* __restrict__ dst) {
    int row = blockIdx.x * 4 + (threadIdx.x >> 6);
    int l = threadIdx.x & 63;
    float4 v;
    if ((row % SP) == 0) {          // wave-uniform
        float4 c = *(const float4*)(cls + l * 4);
        float4 pp = *(const float4*)(pos + l * 4);
        v.x = c.x + pp.x; v.y = c.y + pp.y; v.z = c.z + pp.z; v.w = c.w + pp.w;
        *(float4*)(x + (size_t)row * D + l * 4) = v;
    } else {
        v = *(const float4*)(x + (size_t)row * D + l * 4);
    }
    float s = v.x + v.y + v.z + v.w;
    for (int off = 32; off; off >>= 1) s += __shfl_xor(s, off, 64);
    float mean = s * (1.0f / D);
    float dx0 = v.x - mean, dx1 = v.y - mean, dx2 = v.z - mean, dx3 = v.w - mean;
    float sq = dx0 * dx0 + dx1 * dx1 + dx2 * dx2 + dx3 * dx3;
    for (int off = 32; off; off >>= 1) sq += __shfl_xor(sq, off, 64);
    float rs = rsqrtf(sq * (1.0f / D) + 1e-5f);
    float4 gv = *(const float4*)(gw + l * 4);
    float4 bv = *(const float4*)(bw + l * 4);
    ushort4 o;
    o.x = f2b(dx0 * rs * gv.x + bv.x);
    o.y = f2b(dx1 * rs * gv.y + bv.y);
    o.z = f2b(dx2 * rs * gv.z + bv.z);
    o.w = f2b(dx3 * rs * gv.w + bv.w);
    *(ushort4*)(dst + (size_t)row * D + l * 4) = o;
}

// ---------------------------------------------------------------------------
// Flash attention, stage-once, 8-wave blocks, XCD-swizzled 1D grid:
// bid -> (group g = (bh,quarter), member qg) with all ngq members of a group
// on the same XCD (g & 7). Whole kv-quarter DMA'd to LDS, ONE barrier, each
// wave owns ONE q-tile. 32x32 MFMA, swapped QK^T, in-register base-2 softmax
// without max tracking. Raw bf16 partials; combine divides by total l.
// grid 128*ngq blocks, 512 thr. Runtime tile loop (unrolling spills - R19).
// ---------------------------------------------------------------------------
__global__ __launch_bounds__(512, 4) void attn_stage(const u16* __restrict__ qkv,
                                                     const u16* __restrict__ VTg,
                                                     u16* __restrict__ opart,
                                                     float* __restrict__ lsum,
                                                     int nqt, int ngq) {
    const int bid = blockIdx.x;
    const int xcd = bid & 7, t2 = bid >> 3;
    const int g128 = xcd + 8 * (t2 / ngq);
    const int qg = t2 % ngq;
    const int quarter = g128 >> 5, bh = g128 & 31;
    const int h4 = bh & 3, b = bh >> 2;
    const int t = threadIdx.x;
    const int wv = t >> 6, l = t & 63;
    const int col = l & 31, hh = l >> 5;

    __shared__ u16 Kl[5 * 64 * 64];
    __shared__ u16 Vl[5 * 64 * 64];

    const int kv_start = quarter * 256;
    const int kv_len = (quarter == 3) ? (SP - 768) : 256;   // 256 or 257
    const int ntiles = (kv_len + 63) >> 6;                  // 4 or 5

    const int qt = qg * 8 + wv;            // this wave's q-tile
    const int q0w = qt * 32;

    bf16x8 qf[4];
    {
        int qr = q0w + col; if (qr > S) qr = S;
        const u16* qp = qkv + ((size_t)b * SP + qr) * 768 + h4 * 64 + hh * 8;
#pragma unroll
        for (int c = 0; c < 4; ++c) qf[c] = *(const bf16x8*)(qp + c * 16);
    }

    {
        const int rloc = wv * 8 + (l >> 3);
        const int j = (l & 7) ^ (((rloc >> 3) ^ rloc) & 7);
        for (int tt = 0; tt < ntiles; ++tt) {
            int krow = kv_start + tt * 64 + rloc; if (krow > S) krow = S;
            gload_lds16(qkv + ((size_t)b * SP + krow) * 768 + 256 + h4 * 64 + j * 8,
                        &Kl[(tt * 8 + wv) * 512]);
            gload_lds16(VTg + ((size_t)bh * 64 + rloc) * KVPAD + kv_start + tt * 64 + j * 8,
                        &Vl[(tt * 8 + wv) * 512]);
        }
    }
    __syncthreads();
    if (qt >= nqt) return;

    const int swA = ((col >> 3) ^ col) & 7;
    const int swB = swA ^ 4;

    f32x16 o0, o1;
#pragma unroll
    for (int r = 0; r < 16; ++r) { o0[r] = 0.f; o1[r] = 0.f; }
    float l_run = 0.f;

    for (int tile = 0; tile < ntiles; ++tile) {
        const int kv0 = tile * 64;
        const u16* Kt = &Kl[tile * 4096];
        const u16* Vt = &Vl[tile * 4096];

        f32x16 s0, s1;
#pragma unroll
        for (int r = 0; r < 16; ++r) { s0[r] = 0.f; s1[r] = 0.f; }
        __builtin_amdgcn_s_setprio(1);
#pragma unroll
        for (int c = 0; c < 4; ++c) {
            bf16x8 k0 = *(const bf16x8*)&Kt[col * 64 + (((2 * c + hh) ^ swA) * 8)];
            bf16x8 k1 = *(const bf16x8*)&Kt[(32 + col) * 64 + (((2 * c + hh) ^ swB) * 8)];
            s0 = __builtin_amdgcn_mfma_f32_32x32x16_bf16(k0, qf[c], s0, 0, 0, 0);
            s1 = __builtin_amdgcn_mfma_f32_32x32x16_bf16(k1, qf[c], s1, 0, 0, 0);
        }
        __builtin_amdgcn_s_setprio(0);

        float p[32];
#pragma unroll
        for (int r = 0; r < 16; ++r) { p[r] = s0[r]; p[16 + r] = s1[r]; }

        if (kv0 + 64 > kv_len) {
#pragma unroll
            for (int kvs = 0; kvs < 2; ++kvs)
#pragma unroll
                for (int r = 0; r < 16; ++r) {
                    int kvloc = kvs * 32 + (r & 3) + 8 * (r >> 2) + 4 * hh;
                    if (kv0 + kvloc >= kv_len) p[kvs * 16 + r] = -1e30f;
                }
        }

#pragma unroll
        for (int j = 0; j < 32; ++j) p[j] = exp2f(p[j]);
        {
            float t16[16];
#pragma unroll
            for (int j = 0; j < 16; ++j) t16[j] = p[2 * j] + p[2 * j + 1];
#pragma unroll
            for (int j = 0; j < 8; ++j) t16[j] = t16[j] + t16[j + 8];
#pragma unroll
            for (int j = 0; j < 4; ++j) t16[j] = t16[j] + t16[j + 4];
            l_run += (t16[0] + t16[1]) + (t16[2] + t16[3]);
        }

        __builtin_amdgcn_s_setprio(1);
#pragma unroll
        for (int kvs = 0; kvs < 2; ++kvs) {
            u32 pk[8];
#pragma unroll
            for (int i = 0; i < 8; ++i) pk[i] = pk2(p[kvs * 16 + 2 * i], p[kvs * 16 + 2 * i + 1]);
            u32 ex[4];
#pragma unroll
            for (int kk = 0; kk < 4; ++kk) {
                const int k = (kk < 2) ? kk : kk + 2;
                u32 send = hh ? pk[k] : pk[k + 2];
                ex[kk] = (u32)__shfl_xor((int)send, 32);
            }
#pragma unroll
            for (int cc = 0; cc < 2; ++cc) {
                union { u32 u[4]; bf16x8 v; } pa;
                u32 e0 = ex[cc * 2], e1 = ex[cc * 2 + 1];
                pa.u[0] = hh ? e0 : pk[4 * cc];
                pa.u[1] = hh ? e1 : pk[4 * cc + 1];
                pa.u[2] = hh ? pk[4 * cc + 2] : e0;
                pa.u[3] = hh ? pk[4 * cc + 3] : e1;
                int lch = kvs * 4 + cc * 2 + hh;
                bf16x8 v0 = *(const bf16x8*)&Vt[col * 64 + ((lch ^ swA) * 8)];
                bf16x8 v1 = *(const bf16x8*)&Vt[(32 + col) * 64 + ((lch ^ swB) * 8)];
                o0 = __builtin_amdgcn_mfma_f32_32x32x16_bf16(pa.v, v0, o0, 0, 0, 0);
                o1 = __builtin_amdgcn_mfma_f32_32x32x16_bf16(pa.v, v1, o1, 0, 0, 0);
            }
        }
        __builtin_amdgcn_s_setprio(0);
    }

    float l_full = l_run + __shfl_xor(l_run, 32);
    const size_t obase = ((size_t)quarter * 32 + bh) * SP;
#pragma unroll
    for (int r = 0; r < 16; ++r) {
        int qrow = (r & 3) + 8 * (r >> 2) + 4 * hh;
        int qq = q0w + qrow;
        if (qq < SP) {
            opart[(obase + qq) * 64 + col]      = f2b(o0[r]);
            opart[(obase + qq) * 64 + 32 + col] = f2b(o1[r]);
        }
    }
    if (l < 32) {
        int qq = q0w + l;
        if (qq < SP) lsum[obase + qq] = l_full;
    }
}

// ---------------------------------------------------------------------------
// Fused: x += (Σ raw partials)/(Σ l); lnb = LN2(x).
// ---------------------------------------------------------------------------
__global__ void combine_ln2(const u16* __restrict__ opart, const float* __restrict__ lsum,
                            const float* __restrict__ gw, const float* __restrict__ bw,
                            float* __restrict__ x, u16* __restrict__ lnb) {
    int row = blockIdx.x * 4 + (threadIdx.x >> 6);
    int l = threadIdx.x & 63;
    int b = row / SP, qq = row % SP;
    int h = l >> 4, d0 = (l * 4) & 63;
    int bh = b * 4 + h;
    float csum = 0.f, a0 = 0.f, a1 = 0.f, a2 = 0.f, a3 = 0.f;
#pragma unroll
    for (int i = 0; i < 4; ++i) {
        size_t idx = ((size_t)i * 32 + bh) * SP + qq;
        csum += lsum[idx];
        ushort4 ov = *(const ushort4*)&opart[idx * 64 + d0];
        a0 += b2f(ov.x); a1 += b2f(ov.y); a2 += b2f(ov.z); a3 += b2f(ov.w);
    }
    float inv = 1.0f / csum;
    float4 xv = *(const float4*)(x + (size_t)row * D + l * 4);
    xv.x += a0 * inv; xv.y += a1 * inv; xv.z += a2 * inv; xv.w += a3 * inv;
    *(float4*)(x + (size_t)row * D + l * 4) = xv;

    float s = xv.x + xv.y + xv.z + xv.w;
    for (int off = 32; off; off >>= 1) s += __shfl_xor(s, off, 64);
    float mean = s * (1.0f / D);
    float dx0 = xv.x - mean, dx1 = xv.y - mean, dx2 = xv.z - mean, dx3 = xv.w - mean;
    float sq = dx0 * dx0 + dx1 * dx1 + dx2 * dx2 + dx3 * dx3;
    for (int off = 32; off; off >>= 1) sq += __shfl_xor(sq, off, 64);
    float rs = rsqrtf(sq * (1.0f / D) + 1e-5f);
    float4 gv = *(const float4*)(gw + l * 4);
    float4 bv = *(const float4*)(bw + l * 4);
    ushort4 o;
    o.x = f2b(dx0 * rs * gv.x + bv.x);
    o.y = f2b(dx1 * rs * gv.y + bv.y);
    o.z = f2b(dx2 * rs * gv.z + bv.z);
    o.w = f2b(dx3 * rs * gv.w + bv.w);
    *(ushort4*)(lnb + (size_t)row * D + l * 4) = o;
}

// ---------------------------------------------------------------------------
// Fused: x += Pk0 + Pk1 + b2 (bf16 partials); lnb = LN1_{l+1}(x).
// ---------------------------------------------------------------------------
__global__ void combine2_ln1(const u16* __restrict__ Pkb, const float* __restrict__ b2,
                             const float* __restrict__ gw, const float* __restrict__ bw,
                             float* __restrict__ x, u16* __restrict__ lnb) {
    int row = blockIdx.x * 4 + (threadIdx.x >> 6);
    int l = threadIdx.x & 63;
    ushort4 p0 = *(const ushort4*)(Pkb + (size_t)row * D + l * 4);
    ushort4 p1 = *(const ushort4*)(Pkb + (size_t)N * D + (size_t)row * D + l * 4);
    float4 bv2 = *(const float4*)(b2 + l * 4);
    float4 xv = *(const float4*)(x + (size_t)row * D + l * 4);
    xv.x += b2f(p0.x) + b2f(p1.x) + bv2.x;
    xv.y += b2f(p0.y) + b2f(p1.y) + bv2.y;
    xv.z += b2f(p0.z) + b2f(p1.z) + bv2.z;
    xv.w += b2f(p0.w) + b2f(p1.w) + bv2.w;
    *(float4*)(x + (size_t)row * D + l * 4) = xv;

    float s = xv.x + xv.y + xv.z + xv.w;
    for (int off = 32; off; off >>= 1) s += __shfl_xor(s, off, 64);
    float mean = s * (1.0f / D);
    float dx0 = xv.x - mean, dx1 = xv.y - mean, dx2 = xv.z - mean, dx3 = xv.w - mean;
    float sq = dx0 * dx0 + dx1 * dx1 + dx2 * dx2 + dx3 * dx3;
    for (int off = 32; off; off >>= 1) sq += __shfl_xor(sq, off, 64);
    float rs = rsqrtf(sq * (1.0f / D) + 1e-5f);
    float4 gv = *(const float4*)(gw + l * 4);
    float4 bv = *(const float4*)(bw + l * 4);
    ushort4 o;
    o.x = f2b(dx0 * rs * gv.x + bv.x);
    o.y = f2b(dx1 * rs * gv.y + bv.y);
    o.z = f2b(dx2 * rs * gv.z + bv.z);
    o.w = f2b(dx3 * rs * gv.w + bv.w);
    *(ushort4*)(lnb + (size_t)row * D + l * 4) = o;
}

// ---------------------------------------------------------------------------
// Tail: mlp1 + GELU with fused cls combine + LN2 prologue (redundant per
// f-chunk, cheap & L2-hot). grid (8 f-chunks, B), 256 thr; 2 thr per output.
// fc==0 also writes xc (residual base for tail_mlp2).
// ---------------------------------------------------------------------------
__global__ void tail_mlp1(const u16* __restrict__ opart, const float* __restrict__ lsum,
                          const float* __restrict__ x,
                          const float* __restrict__ g2, const float* __restrict__ b2w,
                          const u16* __restrict__ W1l, const float* __restrict__ b1l,
                          float* __restrict__ xc, float* __restrict__ midc) {
    __shared__ float ln[256];
    __shared__ float red[4];
    const int fc = blockIdx.x, b = blockIdx.y, t = threadIdx.x;
    const int h = t >> 6, dl = t & 63;

    // cls combine + LN2 (same math as old tail_ln)
    float csum = 0.f, a = 0.f;
#pragma unroll
    for (int i = 0; i < 4; ++i) {
        size_t idx = ((size_t)i * 32 + b * 4 + h) * SP;
        csum += lsum[idx];
        a += b2f(opart[idx * 64 + dl]);
    }
    float xv = x[(size_t)b * SP * D + t] + a / csum;
    if (fc == 0) xc[b * D + t] = xv;

    float s = xv;
    for (int off = 32; off; off >>= 1) s += __shfl_xor(s, off, 64);
    if ((t & 63) == 0) red[t >> 6] = s;
    __syncthreads();
    float mean = (red[0] + red[1] + red[2] + red[3]) * (1.0f / D);
    float dx = xv - mean;
    float sq = dx * dx;
    for (int off = 32; off; off >>= 1) sq += __shfl_xor(sq, off, 64);
    __syncthreads();
    if ((t & 63) == 0) red[t >> 6] = sq;
    __syncthreads();
    float var = (red[0] + red[1] + red[2] + red[3]) * (1.0f / D);
    ln[t] = dx * rsqrtf(var + 1e-5f) * g2[t] + b2w[t];
    __syncthreads();

    const int f = fc * 128 + (t >> 1);
    const int half = t & 1;
    const u16* wr = W1l + (size_t)f * D + half * 128;
    const float* lp = &ln[half * 128];
    float acc = 0.f;
#pragma unroll
    for (int d = 0; d < 128; d += 8) {
        bf16x8 wv = *(const bf16x8*)(wr + d);
        const u16* wu = (const u16*)&wv;
#pragma unroll
        for (int j = 0; j < 8; ++j) acc += lp[d + j] * b2f(wu[j]);
    }
    acc += __shfl_xor(acc, 1);
    if (half == 0) {
        float v = acc + b1l[f];
        midc[b * DF + f] = 0.5f * v * (1.0f + erff(v * 0.70710678118654752f));
    }
}

// ---------------------------------------------------------------------------
// Tail stage 3: mlp2 residual. grid (8 d-chunks, B), 256 thr; 8 thr per output.
// ---------------------------------------------------------------------------
__global__ void tail_mlp2(const float* __restrict__ midc,
                          const u16* __restrict__ W2l, const float* __restrict__ b2l,
                          const float* __restrict__ xc, float* __restrict__ xc2) {
    __shared__ float mh[1024];
    const int dc = blockIdx.x, b = blockIdx.y, t = threadIdx.x;
#pragma unroll
    for (int i = 0; i < 4; ++i) mh[t + i * 256] = midc[b * DF + t + i * 256];
    __syncthreads();
    const int dout = dc * 32 + (t >> 3);
    const int oct = t & 7;
    const u16* wr = W2l + (size_t)dout * DF + oct * 128;
    const float* mp = &mh[oct * 128];
    float acc = 0.f;
#pragma unroll
    for (int f = 0; f < 128; f += 8) {
        bf16x8 wv = *(const bf16x8*)(wr + f);
        const u16* wu = (const u16*)&wv;
#pragma unroll
        for (int j = 0; j < 8; ++j) acc += mp[f + j] * b2f(wu[j]);
    }
    acc += __shfl_xor(acc, 1);
    acc += __shfl_xor(acc, 2);
    acc += __shfl_xor(acc, 4);
    if (oct == 0) xc2[b * D + dout] = xc[b * D + dout] + acc + b2l[dout];
}

// ---------------------------------------------------------------------------
__global__ void head_kernel(const float* __restrict__ xc,
                            const float* __restrict__ Wo,
                            const float* __restrict__ bo,
                            float* __restrict__ out) {
    __shared__ float logits[B][O];
    int t = threadIdx.x;
    if (t < B * O) {
        int b = t / O, o = t % O;
        const float* xr = xc + (size_t)b * D;
        float acc = bo[o];
        for (int d = 0; d < D; ++d) acc += xr[d] * Wo[(size_t)o * D + d];
        logits[b][o] = acc;
    }
    __syncthreads();
    if (t < B) {
        float mx = -1e30f;
        for (int o = 0; o < O; ++o) mx = fmaxf(mx, logits[t][o]);
        float s = 0.f, e[O];
        for (int o = 0; o < O; ++o) { e[o] = expf(logits[t][o] - mx); s += e[o]; }
        float inv = 1.0f / s;
        for (int o = 0; o < O; ++o) out[t * O + o] = e[o] * inv;
    }
}

// ---------------------------------------------------------------------------
extern "C" void kernel_launch(void* const* d_in, const int* in_sizes, int n_in,
                              void* d_out, int out_size, void* d_ws, size_t ws_size,
                              hipStream_t stream) {
    const float* images = (const float*)d_in[0];
    const float* Wp     = (const float*)d_in[1];
    const float* bp     = (const float*)d_in[2];
    const float* cls    = (const float*)d_in[3];
    const float* pos    = (const float*)d_in[4];
    const float* ln1_g  = (const float*)d_in[5];
    const float* ln1_b  = (const float*)d_in[6];
    const float* Wq     = (const float*)d_in[7];
    const float* bq     = (const float*)d_in[8];
    const float* Wk     = (const float*)d_in[9];
    const float* bk     = (const float*)d_in[10];
    const float* Wv     = (const float*)d_in[11];
    const float* bv     = (const float*)d_in[12];
    const float* ln2_g  = (const float*)d_in[13];
    const float* ln2_b  = (const float*)d_in[14];
    const float* W1     = (const float*)d_in[15];
    const float* b1     = (const float*)d_in[16];
    const float* W2     = (const float*)d_in[17];
    const float* b2     = (const float*)d_in[18];
    const float* Wo     = (const float*)d_in[19];
    const float* bo     = (const float*)d_in[20];
    float* out = (float*)d_out;

    auto align256 = [](size_t v) { return (v + 255) & ~(size_t)255; };
    char* p = (char*)d_ws;
    float* x      = (float*)p; p += align256((size_t)N * D * 4);
    u16* lnb      = (u16*)p;   p += align256((size_t)N * D * 2);
    u16* qkvbuf   = (u16*)p;   p += align256((size_t)(N + 128) * 768 * 2);  // pad rows
    char* midop   = p;         p += align256((size_t)N * DF * 2);   // mid bf16 / opart bf16 alias
    u16* Pkb      = (u16*)p;   p += align256((size_t)2 * N * D * 2);
    float* lsum   = (float*)p; p += align256((size_t)4 * 32 * SP * 4);
    u16* VTg      = (u16*)p;   p += align256((size_t)32 * 64 * KVPAD * 2);
    u16* imgb     = (u16*)p;   p += align256((size_t)B * S * P * 2);
    u16* Wpb      = (u16*)p;   p += align256((size_t)D * P * 2);
    u16* W1b      = (u16*)p;   p += align256((size_t)L * DF * D * 2);
    u16* W2b      = (u16*)p;   p += align256((size_t)L * D * DF * 2);
    u16* Wqkvb    = (u16*)p;   p += align256((size_t)L * 768 * 256 * 2);
    float* bqkvf  = (float*)p; p += align256((size_t)L * 768 * 4);
    float* xc     = (float*)p; p += align256((size_t)B * D * 4);
    float* midc   = (float*)p; p += align256((size_t)B * DF * 4);
    float* xc2    = (float*)p; p += align256((size_t)B * D * 4);
    u16* mid      = (u16*)midop;
    u16* opart    = (u16*)midop;

    // one-time conversions + QKV weight build (single launch)
    cvt_all<<<dim3(1024, 5), 256, 0, stream>>>(
        images, imgb, B * S * P / 4,
        Wp, Wpb, D * P / 4,
        W1, W1b, L * DF * D / 4,
        W2, W2b, L * D * DF / 4,
        Wq, bq, Wk, bk, Wv, bv, Wqkvb, bqkvf);

    // patch embed as GEMM (M=8192, F=256, K=128); cls + LN1_0 fused
    gemm_bf16<0><<<dim3(2, 128, 1), 256, 0, stream>>>(
        imgb, Wpb, bp, pos, x, nullptr, B * S, D, P, P);
    ln_first<<<N / 4, 256, 0, stream>>>(cls, pos, ln1_g, ln1_b, x, lnb);

    for (int l = 0; l < 3; ++l) {
        gemm_bf16<3><<<dim3(6, 129, 1), 256, 0, stream>>>(
            lnb, Wqkvb + (size_t)l * 768 * 256, bqkvf + (size_t)l * 768,
            nullptr, nullptr, qkvbuf, N, 768, D, D);
        transpose_v<<<dim3(17, 32), 256, 0, stream>>>(qkvbuf, VTg);
        attn_stage<<<640, 512, 0, stream>>>(qkvbuf, VTg, opart, lsum, 33, 5);
        combine_ln2<<<N / 4, 256, 0, stream>>>(opart, lsum, ln2_g + l * D, ln2_b + l * D, x, lnb);
        gemm_bf16<1><<<dim3(8, 129, 1), 256, 0, stream>>>(
            lnb, W1b + (size_t)l * DF * D, b1 + (size_t)l * DF,
            nullptr, nullptr, mid, N, DF, D, D);
        gemm_bf16<4><<<dim3(2, 129, 2), 256, 0, stream>>>(
            mid, W2b + (size_t)l * D * DF, nullptr, nullptr, nullptr, Pkb, N, D, DF, DF / 2);
        combine2_ln1<<<N / 4, 256, 0, stream>>>(Pkb, b2 + (size_t)l * D,
                                                ln1_g + (l + 1) * D, ln1_b + (l + 1) * D, x, lnb);
    }

    // layer 3: only cls rows matter downstream
    {
        const int l = 3;
        gemm_bf16<3><<<dim3(6, 129, 1), 256, 0, stream>>>(
            lnb, Wqkvb + (size_t)l * 768 * 256, bqkvf + (size_t)l * 768,
            nullptr, nullptr, qkvbuf, N, 768, D, D);
        transpose_v<<<dim3(17, 32), 256, 0, stream>>>(qkvbuf, VTg);
        attn_stage<<<128, 512, 0, stream>>>(qkvbuf, VTg, opart, lsum, 1, 1);
        tail_mlp1<<<dim3(8, B), 256, 0, stream>>>(opart, lsum, x,
                                                  ln2_g + l * D, ln2_b + l * D,
                                                  W1b + (size_t)l * DF * D, b1 + (size_t)l * DF,
                                                  xc, midc);
        tail_mlp2<<<dim3(8, B), 256, 0, stream>>>(midc, W2b + (size_t)l * D * DF,
                                                  b2 + (size_t)l * D, xc, xc2);
        head_kernel<<<1, 256, 0, stream>>>(xc2, Wo, bo, out);
    }
}